// Round 16
// baseline (1470.555 us; speedup 1.0000x reference)
//
#include <hip/hip_runtime.h>

#define HID_ 1000
#define NB 256
#define TT 49
#define DIN 192
#define NPAD 1024
#define M_ALL (TT * 256)  // 12544

typedef _Float16 f16;
typedef _Float16 f16x4 __attribute__((ext_vector_type(4)));
typedef _Float16 f16x8 __attribute__((ext_vector_type(8)));
typedef float f32x4 __attribute__((ext_vector_type(4)));
typedef float f32x16 __attribute__((ext_vector_type(16)));
typedef const __attribute__((address_space(1))) unsigned int* gas_u32;
typedef __attribute__((address_space(3))) unsigned int* las_u32;

__device__ __forceinline__ float sigmf_(float x) {
    return 1.0f / (1.0f + __expf(-x));
}
__device__ __forceinline__ float tanhf_(float x) {
    float ax = fabsf(x);
    float e = __expf(-2.0f * ax);
    float t = (1.0f - e) / (1.0f + e);
    return copysignf(t, x);
}

// Vectorized weight convert: fp32 [4*HID_][K] -> f16 [4][1024][KPADv], zero-pad.
__global__ __launch_bounds__(256) void conv_weight_v(
    const float* __restrict__ src, f16* __restrict__ dst, int K, int KPADv, int total8) {
    int idx = blockIdx.x * blockDim.x + threadIdx.x;
    if (idx >= total8) return;
    const int kpw = KPADv >> 3;
    const int kp = (idx % kpw) << 3;
    const int rest = idx / kpw;          // g*1024 + np
    const int np = rest & 1023;
    const int g = rest >> 10;
    f16x8 v = {};
    if (np < HID_ && kp < K) {
        const float* sp = src + (size_t)(g * HID_ + np) * K + kp;
        float4 a = *(const float4*)sp;
        float4 b = *(const float4*)(sp + 4);
        v[0] = (f16)a.x; v[1] = (f16)a.y; v[2] = (f16)a.z; v[3] = (f16)a.w;
        v[4] = (f16)b.x; v[5] = (f16)b.y; v[6] = (f16)b.z; v[7] = (f16)b.w;
    }
    *(f16x8*)(dst + (size_t)rest * KPADv + kp) = v;
}

// Vectorized enc_in transpose-convert: [B][T][D] fp32 -> [T][B][D] f16.
__global__ __launch_bounds__(256) void conv_x_v(
    const float* __restrict__ src, f16* __restrict__ dst, int total8) {
    int idx = blockIdx.x * blockDim.x + threadIdx.x;
    if (idx >= total8) return;
    const int kp = (idx % (DIN / 8)) << 3;
    const int rest = idx / (DIN / 8);    // t*NB + b
    const int b = rest & 255;
    const int t = rest >> 8;
    const float* sp = src + ((size_t)b * TT + t) * DIN + kp;
    float4 a = *(const float4*)sp;
    float4 c = *(const float4*)(sp + 4);
    f16x8 v;
    v[0] = (f16)a.x; v[1] = (f16)a.y; v[2] = (f16)a.z; v[3] = (f16)a.w;
    v[4] = (f16)c.x; v[5] = (f16)c.y; v[6] = (f16)c.z; v[7] = (f16)c.w;
    *(f16x8*)(dst + (size_t)rest * DIN + kp) = v;
}

// bias_c[4][NPAD] fp32 = b_ih + b_hh (zero-padded)
__global__ void conv_bias(const float* __restrict__ bih, const float* __restrict__ bhh,
                          float* __restrict__ dst) {
    int idx = blockIdx.x * blockDim.x + threadIdx.x;
    if (idx < 4 * NPAD) {
        int np = idx & (NPAD - 1);
        int g = idx >> 10;
        float v = 0.0f;
        if (np < HID_) v = bih[g * HID_ + np] + bhh[g * HID_ + np];
        dst[idx] = v;
    }
}

// Pipelined GEMM: pre2 = A @ W^T + bias (r15 version, unchanged).
// 256x256 tile, BK=32, 4-buf LDS rotation, counted vmcnt, setprio.
// Output scatter in rec's 32x32-fragment order.
__global__ __launch_bounds__(512) void gemm8(
    const f16* __restrict__ A, int lda, int nkt,
    const f16* __restrict__ W, int ldw,
    const float* __restrict__ bias,
    f16* __restrict__ pre2) {
    __shared__ f16 lds[4][2][8192];  // [buf][A=0/B=1][256 rows x 32 k]
    const int id = blockIdx.x;
    const int sw = (id & 7) * (gridDim.x >> 3) + (id >> 3);  // 784 % 8 == 0
    const int mt = sw >> 4;   // 0..48
    const int nt = sw & 15;   // 0..15
    const int m0 = mt << 8, n0 = nt << 8;
    const int tid = threadIdx.x;
    const int w = tid >> 6, lane = tid & 63;
    const int r = lane & 15, u = lane >> 4;
    const int wr = w >> 2, wc = w & 3;

    const int srow = (w << 5) + (lane >> 2);
    const int pslot = lane & 3;

    f32x4 acc[8][4];
#pragma unroll
    for (int mf = 0; mf < 8; mf++)
#pragma unroll
        for (int nf = 0; nf < 4; nf++) acc[mf][nf] = (f32x4){0.f, 0.f, 0.f, 0.f};

    auto STAGE = [&](int kt, int o) {
        const int b = kt & 3;
        const int row = srow + (o << 4);
        const int ls = pslot ^ (row & 3);
        const f16* ga = A + (size_t)(m0 + row) * lda + kt * 32 + ls * 8;
        const f16* gb = W + (size_t)(n0 + row) * ldw + kt * 32 + ls * 8;
        f16* da = &lds[b][0][0] + (w << 10) + (o << 9);
        f16* db = &lds[b][1][0] + (w << 10) + (o << 9);
        __builtin_amdgcn_global_load_lds((gas_u32)ga, (las_u32)da, 16, 0, 0);
        __builtin_amdgcn_global_load_lds((gas_u32)gb, (las_u32)db, 16, 0, 0);
    };
    auto RDA = [&](int b, int fr) -> f16x8 {
        const int row = (wr << 7) + fr * 16 + r;
        return *(const f16x8*)(&lds[b][0][0] + row * 32 + ((u ^ (row & 3)) << 3));
    };
    auto RDB = [&](int b, int nf) -> f16x8 {
        const int row = (wc << 6) + nf * 16 + r;
        return *(const f16x8*)(&lds[b][1][0] + row * 32 + ((u ^ (row & 3)) << 3));
    };

    STAGE(0, 0); STAGE(0, 1); STAGE(1, 0); STAGE(1, 1);
    asm volatile("s_waitcnt vmcnt(4)" ::: "memory");
    __builtin_amdgcn_s_barrier();
    __builtin_amdgcn_sched_barrier(0);

    for (int kt = 0; kt < nkt; kt++) {
        const int b = kt & 3;
        const bool st = (kt + 2) < nkt;
        f16x8 bv[4], av[4];
#pragma unroll
        for (int nf = 0; nf < 4; nf++) bv[nf] = RDB(b, nf);
#pragma unroll
        for (int mf = 0; mf < 4; mf++) av[mf] = RDA(b, mf);
        if (st) STAGE(kt + 2, 0);
        __builtin_amdgcn_s_barrier();
        __builtin_amdgcn_s_setprio(1);
#pragma unroll
        for (int mf = 0; mf < 4; mf++)
#pragma unroll
            for (int nf = 0; nf < 4; nf++)
                acc[mf][nf] = __builtin_amdgcn_mfma_f32_16x16x32_f16(
                    av[mf], bv[nf], acc[mf][nf], 0, 0, 0);
        __builtin_amdgcn_s_setprio(0);
        __builtin_amdgcn_s_barrier();
#pragma unroll
        for (int mf = 0; mf < 4; mf++) av[mf] = RDA(b, 4 + mf);
        if (st) STAGE(kt + 2, 1);
        __builtin_amdgcn_s_barrier();
        __builtin_amdgcn_s_setprio(1);
#pragma unroll
        for (int mf = 0; mf < 4; mf++)
#pragma unroll
            for (int nf = 0; nf < 4; nf++)
                acc[4 + mf][nf] = __builtin_amdgcn_mfma_f32_16x16x32_f16(
                    av[mf], bv[nf], acc[4 + mf][nf], 0, 0, 0);
        __builtin_amdgcn_s_setprio(0);
        if (st) asm volatile("s_waitcnt vmcnt(4)" ::: "memory");
        else    asm volatile("s_waitcnt vmcnt(0)" ::: "memory");
        __builtin_amdgcn_s_barrier();
        __builtin_amdgcn_sched_barrier(0);
    }

#pragma unroll
    for (int nf = 0; nf < 4; nf++) {
        const int gcol = n0 + (wc << 6) + nf * 16 + r;
        const float bj = bias[gcol];
        const int g = gcol >> 10;
        const int jt2 = (gcol & 1023) >> 5;
        const int col32 = gcol & 31;
        const int lane2 = col32 + ((u & 1) << 5);
#pragma unroll
        for (int mf = 0; mf < 8; mf++) {
            const int grow = m0 + (wr << 7) + mf * 16 + (u << 2);  // q=0 row
            const int bt2 = (grow >> 5) & 7;
            const int regbase = ((mf & 1) << 3) + ((u >> 1) << 2);
            f16x4 hv;
#pragma unroll
            for (int q = 0; q < 4; q++) hv[q] = (f16)(acc[mf][nf][q] + bj);
            *(f16x4*)(pre2 + ((((size_t)mt * 8 + bt2) * 32 + jt2) * 4 + g) * 1024 +
                      lane2 * 16 + regbase) = hv;
        }
    }
}

// Persistent per-layer recurrent kernel — r14/r15 structure with TAGGED-DATA
// publish: h is written as 8B atomic {f16x2 data, tag = t+1} into hall2;
// consumers spin directly on the uint2 words they stage (each thread polls
// its own 32B) — the spin load IS the data fetch. No flags, no fetch_add,
// no drain-before-signal. Replay-safe: identical inputs -> previous replay's
// tagged values equal this replay's; poison tag 0xAAAAAAAA never matches.
// Plain f16 hall still written (4B/thread) for next layer's gemm8 A-source.
__global__ __launch_bounds__(512, 2) void rec_persist(
    const f16* __restrict__ Whh, const f16* __restrict__ pre2,
    f16* __restrict__ hall, uint2* __restrict__ hall2,
    float* __restrict__ outl) {
    __shared__ __align__(16) char smem[64 * 1024];  // h tile [32 rows][2048B] XOR5-swizzled
    __shared__ float pl[2 * 4 * 32 * 34];           // [kh][gate][row][34] partials
    const int bid = blockIdx.x;
    const int bt = bid & 7;
    const int jt = bid >> 3;
    const int b0 = bt << 5;
    const int jc0 = jt << 5;
    const int tid = threadIdx.x;
    const int w = tid >> 6;
    const int g = w >> 1;
    const int kh = w & 1;
    const int lane = tid & 63;
    const int row = lane & 31;
    const int kg = lane >> 5;

    f16x8 wreg[32];
    {
        const f16* wp = Whh + ((size_t)(g * NPAD + jc0 + row)) * NPAD + (kh << 9) + (kg << 3);
#pragma unroll
        for (int ks = 0; ks < 32; ks++) wreg[ks] = *(const f16x8*)(wp + ks * 16);
    }

    const int eb = tid >> 4;
    const int ej = (tid & 15) << 1;
    float cv[2] = {0.f, 0.f};
    const size_t preblk = ((((size_t)bt) * 32 + jt) * 4 + g) * 1024 + lane * 16;

    auto LOADP = [&](int tindex, f16x8& pa, f16x8& pb) {
        if (kh == 0) {
            const f16* pp = pre2 + (size_t)tindex * 8 * 32 * 4 * 1024 + preblk;
            pa = *(const f16x8*)pp;
            pb = *(const f16x8*)(pp + 8);
        }
    };

    auto STEP = [&](int t, f16x8& pc0, f16x8& pc1, f16x8& pn0, f16x8& pn1) {
        LOADP(t + 1 < TT ? t + 1 : t, pn0, pn1);

        if (t > 0) {
            // stage h[t-1] rows b0..b0+31 -> LDS, spinning on per-word tags.
            const uint2* hbase = hall2 + (size_t)(t - 1) * NB * 512;
            const unsigned wanted = (unsigned)t;  // written at step t-1 with tag (t-1)+1
#pragma unroll
            for (int i = 0; i < 8; i++) {
                int c = tid + (i << 9);
                int srow = c >> 7;         // 0..31
                int cb = c & 127;          // 16B chunk within row (1024 f16 = 128 chunks)
                const uint2* hp = hbase + (size_t)(b0 + srow) * 512 + (cb << 2);
                uint2 d0, d1, d2, d3;
                while (true) {
                    d0 = __hip_atomic_load(hp + 0, __ATOMIC_RELAXED, __HIP_MEMORY_SCOPE_AGENT);
                    d1 = __hip_atomic_load(hp + 1, __ATOMIC_RELAXED, __HIP_MEMORY_SCOPE_AGENT);
                    d2 = __hip_atomic_load(hp + 2, __ATOMIC_RELAXED, __HIP_MEMORY_SCOPE_AGENT);
                    d3 = __hip_atomic_load(hp + 3, __ATOMIC_RELAXED, __HIP_MEMORY_SCOPE_AGENT);
                    if (d0.y == wanted && d1.y == wanted && d2.y == wanted && d3.y == wanted)
                        break;
                }
                uint4 v = make_uint4(d0.x, d1.x, d2.x, d3.x);
                *(uint4*)(smem + srow * 2048 + (((unsigned)cb << 4) ^ ((unsigned)srow << 4))) = v;
            }
        }
        __syncthreads();  // B1: h tile staged

        f32x16 acc;
#pragma unroll
        for (int reg = 0; reg < 16; reg++)
            acc[reg] = (kh == 0) ? (float)(reg < 8 ? pc0[reg] : pc1[reg - 8]) : 0.f;

        if (t > 0) {
#pragma unroll
            for (int ks = 0; ks < 32; ks++) {
                const int bc = (kh << 10) + ks * 32 + (kg << 4);
                f16x8 a = *(const f16x8*)(smem + row * 2048 + (bc ^ (row << 4)));
                acc = __builtin_amdgcn_mfma_f32_32x32x16_f16(a, wreg[ks], acc, 0, 0, 0);
            }
        }

#pragma unroll
        for (int reg = 0; reg < 16; reg++) {
            const int prow = (reg & 3) + ((reg >> 2) << 3) + (kg << 2);
            pl[((kh * 4 + g) * 32 + prow) * 34 + row] = acc[reg];
        }
        __syncthreads();  // B2: partials ready

        float hvv[2];
        {
            float gv[4][2];
#pragma unroll
            for (int gate = 0; gate < 4; gate++) {
                float2 p0 = *(const float2*)&pl[((0 * 4 + gate) * 32 + eb) * 34 + ej];
                float2 p1 = *(const float2*)&pl[((1 * 4 + gate) * 32 + eb) * 34 + ej];
                gv[gate][0] = p0.x + p1.x;
                gv[gate][1] = p0.y + p1.y;
            }
#pragma unroll
            for (int q = 0; q < 2; q++) {
                float cn = sigmf_(gv[1][q]) * cv[q] + sigmf_(gv[0][q]) * tanhf_(gv[2][q]);
                hvv[q] = sigmf_(gv[3][q]) * tanhf_(cn);
                cv[q] = cn;
            }
        }
        // publish: tagged 8B atomic (signal+data) + plain f16 copy for gemm8
        {
            union { f16 h2[2]; unsigned uu; } cvt;
            cvt.h2[0] = (f16)hvv[0];
            cvt.h2[1] = (f16)hvv[1];
            *(unsigned*)(hall + ((size_t)t * NB + b0 + eb) * NPAD + jc0 + ej) = cvt.uu;
            uint2 pkt = make_uint2(cvt.uu, (unsigned)(t + 1));
            __hip_atomic_store(hall2 + ((size_t)t * NB + b0 + eb) * 512 + ((jc0 + ej) >> 1),
                               pkt, __ATOMIC_RELAXED, __HIP_MEMORY_SCOPE_AGENT);
        }
        const int col = jc0 + ej;
        if (col < HID_) {
            *(float2*)(outl + ((size_t)(b0 + eb) * TT + t) * HID_ + col) =
                make_float2(hvv[0], hvv[1]);
        }
        __syncthreads();  // B3: pl reads done before next step's writes; smem safe
    };

    f16x8 pA0 = {}, pA1 = {}, pB0 = {}, pB1 = {};
    LOADP(0, pA0, pA1);
    for (int t = 0; t < TT; t += 2) {
        STEP(t, pA0, pA1, pB0, pB1);
        if (t + 1 < TT) STEP(t + 1, pB0, pB1, pA0, pA1);
    }
}

extern "C" void kernel_launch(void* const* d_in, const int* in_sizes, int n_in,
                              void* d_out, int out_size, void* d_ws, size_t ws_size,
                              hipStream_t stream) {
    const float* enc_in = (const float*)d_in[0];
    const float* W_ih[3] = {(const float*)d_in[1], (const float*)d_in[5], (const float*)d_in[9]};
    const float* W_hh[3] = {(const float*)d_in[2], (const float*)d_in[6], (const float*)d_in[10]};
    const float* b_ih[3] = {(const float*)d_in[3], (const float*)d_in[7], (const float*)d_in[11]};
    const float* b_hh[3] = {(const float*)d_in[4], (const float*)d_in[8], (const float*)d_in[12]};
    float* out = (float*)d_out;

    char* ws = (char*)d_ws;
    size_t off = 0;
    auto alloc = [&](size_t bytes) {
        char* p = ws + off;
        off += (bytes + 255) & ~(size_t)255;
        return p;
    };
    f16* Wih_c[3];
    f16* Whh_c[3];
    Wih_c[0] = (f16*)alloc(4ull * NPAD * DIN * sizeof(f16));
    Whh_c[0] = (f16*)alloc(4ull * NPAD * NPAD * sizeof(f16));
    Wih_c[1] = (f16*)alloc(4ull * NPAD * NPAD * sizeof(f16));
    Whh_c[1] = (f16*)alloc(4ull * NPAD * NPAD * sizeof(f16));
    Wih_c[2] = (f16*)alloc(4ull * NPAD * NPAD * sizeof(f16));
    Whh_c[2] = (f16*)alloc(4ull * NPAD * NPAD * sizeof(f16));
    float* bias_c[3];
    for (int l = 0; l < 3; l++) bias_c[l] = (float*)alloc(4ull * NPAD * sizeof(float));
    f16* xbf = (f16*)alloc((size_t)TT * NB * DIN * sizeof(f16));
    f16* hall[3];
    for (int l = 0; l < 3; l++) hall[l] = (f16*)alloc((size_t)TT * NB * NPAD * sizeof(f16));
    uint2* hall2[3];
    for (int l = 0; l < 3; l++) hall2[l] = (uint2*)alloc((size_t)TT * NB * 512 * sizeof(uint2));
    f16* pre2 = (f16*)alloc((size_t)M_ALL * 4096 * sizeof(f16));

    {
        int t8_l0 = 4 * NPAD * DIN / 8;
        conv_weight_v<<<(t8_l0 + 255) / 256, 256, 0, stream>>>(W_ih[0], Wih_c[0], DIN, DIN, t8_l0);
        int t8 = 4 * NPAD * NPAD / 8;
        conv_weight_v<<<(t8 + 255) / 256, 256, 0, stream>>>(W_hh[0], Whh_c[0], HID_, NPAD, t8);
        conv_weight_v<<<(t8 + 255) / 256, 256, 0, stream>>>(W_ih[1], Wih_c[1], HID_, NPAD, t8);
        conv_weight_v<<<(t8 + 255) / 256, 256, 0, stream>>>(W_hh[1], Whh_c[1], HID_, NPAD, t8);
        conv_weight_v<<<(t8 + 255) / 256, 256, 0, stream>>>(W_ih[2], Wih_c[2], HID_, NPAD, t8);
        conv_weight_v<<<(t8 + 255) / 256, 256, 0, stream>>>(W_hh[2], Whh_c[2], HID_, NPAD, t8);
    }
    {
        int t8x = TT * NB * (DIN / 8);
        conv_x_v<<<(t8x + 255) / 256, 256, 0, stream>>>(enc_in, xbf, t8x);
    }
    for (int l = 0; l < 3; l++)
        conv_bias<<<(4 * NPAD + 255) / 256, 256, 0, stream>>>(b_ih[l], b_hh[l], bias_c[l]);

    for (int l = 0; l < 3; l++) {
        if (l == 0)
            gemm8<<<784, 512, 0, stream>>>(xbf, DIN, DIN / 32, Wih_c[0], DIN,
                                           bias_c[0], pre2);
        else
            gemm8<<<784, 512, 0, stream>>>(hall[l - 1], NPAD, NPAD / 32, Wih_c[l], NPAD,
                                           bias_c[l], pre2);
        rec_persist<<<256, 512, 0, stream>>>(
            Whh_c[l], pre2, hall[l], hall2[l],
            out + (size_t)l * NB * TT * HID_);
    }
}

// Round 17
// 1054.081 us; speedup vs baseline: 1.3951x; 1.3951x over previous
//
#include <hip/hip_runtime.h>

#define HID_ 1000
#define NB 256
#define TT 49
#define DIN 192
#define NPAD 1024
#define M_ALL (TT * 256)  // 12544

typedef _Float16 f16;
typedef _Float16 f16x4 __attribute__((ext_vector_type(4)));
typedef _Float16 f16x8 __attribute__((ext_vector_type(8)));
typedef float f32x4 __attribute__((ext_vector_type(4)));
typedef float f32x16 __attribute__((ext_vector_type(16)));
typedef const __attribute__((address_space(1))) unsigned int* gas_u32;
typedef __attribute__((address_space(3))) unsigned int* las_u32;

__device__ __forceinline__ float sigmf_(float x) {
    return 1.0f / (1.0f + __expf(-x));
}
__device__ __forceinline__ float tanhf_(float x) {
    float ax = fabsf(x);
    float e = __expf(-2.0f * ax);
    float t = (1.0f - e) / (1.0f + e);
    return copysignf(t, x);
}

// Vectorized weight convert: fp32 [4*HID_][K] -> f16 [4][1024][KPADv], zero-pad.
__global__ __launch_bounds__(256) void conv_weight_v(
    const float* __restrict__ src, f16* __restrict__ dst, int K, int KPADv, int total8) {
    int idx = blockIdx.x * blockDim.x + threadIdx.x;
    if (idx >= total8) return;
    const int kpw = KPADv >> 3;
    const int kp = (idx % kpw) << 3;
    const int rest = idx / kpw;          // g*1024 + np
    const int np = rest & 1023;
    const int g = rest >> 10;
    f16x8 v = {};
    if (np < HID_ && kp < K) {
        const float* sp = src + (size_t)(g * HID_ + np) * K + kp;
        float4 a = *(const float4*)sp;
        float4 b = *(const float4*)(sp + 4);
        v[0] = (f16)a.x; v[1] = (f16)a.y; v[2] = (f16)a.z; v[3] = (f16)a.w;
        v[4] = (f16)b.x; v[5] = (f16)b.y; v[6] = (f16)b.z; v[7] = (f16)b.w;
    }
    *(f16x8*)(dst + (size_t)rest * KPADv + kp) = v;
}

// Vectorized enc_in transpose-convert: [B][T][D] fp32 -> [T][B][D] f16.
__global__ __launch_bounds__(256) void conv_x_v(
    const float* __restrict__ src, f16* __restrict__ dst, int total8) {
    int idx = blockIdx.x * blockDim.x + threadIdx.x;
    if (idx >= total8) return;
    const int kp = (idx % (DIN / 8)) << 3;
    const int rest = idx / (DIN / 8);    // t*NB + b
    const int b = rest & 255;
    const int t = rest >> 8;
    const float* sp = src + ((size_t)b * TT + t) * DIN + kp;
    float4 a = *(const float4*)sp;
    float4 c = *(const float4*)(sp + 4);
    f16x8 v;
    v[0] = (f16)a.x; v[1] = (f16)a.y; v[2] = (f16)a.z; v[3] = (f16)a.w;
    v[4] = (f16)c.x; v[5] = (f16)c.y; v[6] = (f16)c.z; v[7] = (f16)c.w;
    *(f16x8*)(dst + (size_t)rest * DIN + kp) = v;
}

// bias_c[4][NPAD] fp32 = b_ih + b_hh (zero-padded)
__global__ void conv_bias(const float* __restrict__ bih, const float* __restrict__ bhh,
                          float* __restrict__ dst) {
    int idx = blockIdx.x * blockDim.x + threadIdx.x;
    if (idx < 4 * NPAD) {
        int np = idx & (NPAD - 1);
        int g = idx >> 10;
        float v = 0.0f;
        if (np < HID_) v = bih[g * HID_ + np] + bhh[g * HID_ + np];
        dst[idx] = v;
    }
}

// Pipelined GEMM: pre2 = A @ W^T + bias. 256x256 tile, BK=32, 4-buf LDS
// rotation, counted vmcnt (never 0 in steady state), raw barriers, setprio.
// Output scatter in rec's 32x32-fragment order. (r15 version, best measured.)
__global__ __launch_bounds__(512) void gemm8(
    const f16* __restrict__ A, int lda, int nkt,
    const f16* __restrict__ W, int ldw,
    const float* __restrict__ bias,
    f16* __restrict__ pre2) {
    __shared__ f16 lds[4][2][8192];  // [buf][A=0/B=1][256 rows x 32 k]
    const int id = blockIdx.x;
    const int sw = (id & 7) * (gridDim.x >> 3) + (id >> 3);  // 784 % 8 == 0
    const int mt = sw >> 4;   // 0..48
    const int nt = sw & 15;   // 0..15
    const int m0 = mt << 8, n0 = nt << 8;
    const int tid = threadIdx.x;
    const int w = tid >> 6, lane = tid & 63;
    const int r = lane & 15, u = lane >> 4;
    const int wr = w >> 2, wc = w & 3;

    const int srow = (w << 5) + (lane >> 2);
    const int pslot = lane & 3;

    f32x4 acc[8][4];
#pragma unroll
    for (int mf = 0; mf < 8; mf++)
#pragma unroll
        for (int nf = 0; nf < 4; nf++) acc[mf][nf] = (f32x4){0.f, 0.f, 0.f, 0.f};

    auto STAGE = [&](int kt, int o) {
        const int b = kt & 3;
        const int row = srow + (o << 4);
        const int ls = pslot ^ (row & 3);
        const f16* ga = A + (size_t)(m0 + row) * lda + kt * 32 + ls * 8;
        const f16* gb = W + (size_t)(n0 + row) * ldw + kt * 32 + ls * 8;
        f16* da = &lds[b][0][0] + (w << 10) + (o << 9);
        f16* db = &lds[b][1][0] + (w << 10) + (o << 9);
        __builtin_amdgcn_global_load_lds((gas_u32)ga, (las_u32)da, 16, 0, 0);
        __builtin_amdgcn_global_load_lds((gas_u32)gb, (las_u32)db, 16, 0, 0);
    };
    auto RDA = [&](int b, int fr) -> f16x8 {
        const int row = (wr << 7) + fr * 16 + r;
        return *(const f16x8*)(&lds[b][0][0] + row * 32 + ((u ^ (row & 3)) << 3));
    };
    auto RDB = [&](int b, int nf) -> f16x8 {
        const int row = (wc << 6) + nf * 16 + r;
        return *(const f16x8*)(&lds[b][1][0] + row * 32 + ((u ^ (row & 3)) << 3));
    };

    STAGE(0, 0); STAGE(0, 1); STAGE(1, 0); STAGE(1, 1);
    asm volatile("s_waitcnt vmcnt(4)" ::: "memory");
    __builtin_amdgcn_s_barrier();
    __builtin_amdgcn_sched_barrier(0);

    for (int kt = 0; kt < nkt; kt++) {
        const int b = kt & 3;
        const bool st = (kt + 2) < nkt;
        f16x8 bv[4], av[4];
#pragma unroll
        for (int nf = 0; nf < 4; nf++) bv[nf] = RDB(b, nf);
#pragma unroll
        for (int mf = 0; mf < 4; mf++) av[mf] = RDA(b, mf);
        if (st) STAGE(kt + 2, 0);
        __builtin_amdgcn_s_barrier();
        __builtin_amdgcn_s_setprio(1);
#pragma unroll
        for (int mf = 0; mf < 4; mf++)
#pragma unroll
            for (int nf = 0; nf < 4; nf++)
                acc[mf][nf] = __builtin_amdgcn_mfma_f32_16x16x32_f16(
                    av[mf], bv[nf], acc[mf][nf], 0, 0, 0);
        __builtin_amdgcn_s_setprio(0);
        __builtin_amdgcn_s_barrier();
#pragma unroll
        for (int mf = 0; mf < 4; mf++) av[mf] = RDA(b, 4 + mf);
        if (st) STAGE(kt + 2, 1);
        __builtin_amdgcn_s_barrier();
        __builtin_amdgcn_s_setprio(1);
#pragma unroll
        for (int mf = 0; mf < 4; mf++)
#pragma unroll
            for (int nf = 0; nf < 4; nf++)
                acc[4 + mf][nf] = __builtin_amdgcn_mfma_f32_16x16x32_f16(
                    av[mf], bv[nf], acc[4 + mf][nf], 0, 0, 0);
        __builtin_amdgcn_s_setprio(0);
        if (st) asm volatile("s_waitcnt vmcnt(4)" ::: "memory");
        else    asm volatile("s_waitcnt vmcnt(0)" ::: "memory");
        __builtin_amdgcn_s_barrier();
        __builtin_amdgcn_sched_barrier(0);
    }

#pragma unroll
    for (int nf = 0; nf < 4; nf++) {
        const int gcol = n0 + (wc << 6) + nf * 16 + r;
        const float bj = bias[gcol];
        const int g = gcol >> 10;
        const int jt2 = (gcol & 1023) >> 5;
        const int col32 = gcol & 31;
        const int lane2 = col32 + ((u & 1) << 5);
#pragma unroll
        for (int mf = 0; mf < 8; mf++) {
            const int grow = m0 + (wr << 7) + mf * 16 + (u << 2);  // q=0 row
            const int bt2 = (grow >> 5) & 7;
            const int regbase = ((mf & 1) << 3) + ((u >> 1) << 2);
            f16x4 hv;
#pragma unroll
            for (int q = 0; q < 4; q++) hv[q] = (f16)(acc[mf][nf][q] + bj);
            *(f16x4*)(pre2 + ((((size_t)mt * 8 + bt2) * 32 + jt2) * 4 + g) * 1024 +
                      lane2 * 16 + regbase) = hv;
        }
    }
}

// Persistent per-layer recurrent kernel — r14/r15 version verbatim (best: 238us).
__global__ __launch_bounds__(512, 2) void rec_persist(
    const f16* __restrict__ Whh, const f16* __restrict__ pre2,
    f16* __restrict__ hall, float* __restrict__ outl,
    unsigned int* __restrict__ flags) {
    __shared__ __align__(16) char smem[64 * 1024];  // h tile [32 rows][2048B] XOR5-swizzled
    __shared__ float pl[2 * 4 * 32 * 34];           // [kh][gate][row][34] partials
    const int bid = blockIdx.x;
    const int bt = bid & 7;
    const int jt = bid >> 3;
    const int b0 = bt << 5;
    const int jc0 = jt << 5;
    const int tid = threadIdx.x;
    const int w = tid >> 6;
    const int g = w >> 1;
    const int kh = w & 1;
    const int lane = tid & 63;
    const int row = lane & 31;
    const int kg = lane >> 5;

    f16x8 wreg[32];
    {
        const f16* wp = Whh + ((size_t)(g * NPAD + jc0 + row)) * NPAD + (kh << 9) + (kg << 3);
#pragma unroll
        for (int ks = 0; ks < 32; ks++) wreg[ks] = *(const f16x8*)(wp + ks * 16);
    }

    const int eb = tid >> 4;
    const int ej = (tid & 15) << 1;
    float cv[2] = {0.f, 0.f};
    unsigned int* myflags = flags + bt * TT;
    const size_t preblk = ((((size_t)bt) * 32 + jt) * 4 + g) * 1024 + lane * 16;

    auto LOADP = [&](int tindex, f16x8& pa, f16x8& pb) {
        if (kh == 0) {
            const f16* pp = pre2 + (size_t)tindex * 8 * 32 * 4 * 1024 + preblk;
            pa = *(const f16x8*)pp;
            pb = *(const f16x8*)(pp + 8);
        }
    };

    auto STEP = [&](int t, f16x8& pc0, f16x8& pc1, f16x8& pn0, f16x8& pn1) {
        LOADP(t + 1 < TT ? t + 1 : t, pn0, pn1);

        if (t > 0) {
            while (__hip_atomic_load(myflags + (t - 1), __ATOMIC_RELAXED,
                                     __HIP_MEMORY_SCOPE_AGENT) < 32u) {}
            asm volatile("" ::: "memory");
            const f16* hread = hall + (size_t)(t - 1) * NB * NPAD;
#pragma unroll
            for (int i = 0; i < 8; i++) {
                int c = tid + (i << 9);
                int srow = c >> 7;
                int cb = (c & 127) << 4;
                f16x8 v = *(const f16x8*)(hread + (size_t)(b0 + srow) * NPAD + (cb >> 1));
                *(f16x8*)(smem + srow * 2048 + (cb ^ (srow << 4))) = v;
            }
        }
        __syncthreads();  // B1: h tile staged

        f32x16 acc;
#pragma unroll
        for (int reg = 0; reg < 16; reg++)
            acc[reg] = (kh == 0) ? (float)(reg < 8 ? pc0[reg] : pc1[reg - 8]) : 0.f;

        if (t > 0) {
#pragma unroll
            for (int ks = 0; ks < 32; ks++) {
                const int bc = (kh << 10) + ks * 32 + (kg << 4);
                f16x8 a = *(const f16x8*)(smem + row * 2048 + (bc ^ (row << 4)));
                acc = __builtin_amdgcn_mfma_f32_32x32x16_f16(a, wreg[ks], acc, 0, 0, 0);
            }
        }

#pragma unroll
        for (int reg = 0; reg < 16; reg++) {
            const int prow = (reg & 3) + ((reg >> 2) << 3) + (kg << 2);
            pl[((kh * 4 + g) * 32 + prow) * 34 + row] = acc[reg];
        }
        __syncthreads();  // B2: partials ready

        float hvv[2];
        {
            float gv[4][2];
#pragma unroll
            for (int gate = 0; gate < 4; gate++) {
                float2 p0 = *(const float2*)&pl[((0 * 4 + gate) * 32 + eb) * 34 + ej];
                float2 p1 = *(const float2*)&pl[((1 * 4 + gate) * 32 + eb) * 34 + ej];
                gv[gate][0] = p0.x + p1.x;
                gv[gate][1] = p0.y + p1.y;
            }
#pragma unroll
            for (int q = 0; q < 2; q++) {
                float cn = sigmf_(gv[1][q]) * cv[q] + sigmf_(gv[0][q]) * tanhf_(gv[2][q]);
                hvv[q] = sigmf_(gv[3][q]) * tanhf_(cn);
                cv[q] = cn;
            }
        }
        {
            union { f16 h2[2]; unsigned uu; } cvt;
            cvt.h2[0] = (f16)hvv[0];
            cvt.h2[1] = (f16)hvv[1];
            __hip_atomic_store(
                (unsigned*)(hall + ((size_t)t * NB + b0 + eb) * NPAD + jc0 + ej), cvt.uu,
                __ATOMIC_RELAXED, __HIP_MEMORY_SCOPE_AGENT);
        }
        __syncthreads();  // B3: vmcnt drained -> h stores visible; pl reads done
        if (tid == 0)
            __hip_atomic_fetch_add(myflags + t, 1u, __ATOMIC_RELAXED, __HIP_MEMORY_SCOPE_AGENT);
        const int col = jc0 + ej;
        if (col < HID_) {
            *(float2*)(outl + ((size_t)(b0 + eb) * TT + t) * HID_ + col) =
                make_float2(hvv[0], hvv[1]);
        }
    };

    f16x8 pA0 = {}, pA1 = {}, pB0 = {}, pB1 = {};
    LOADP(0, pA0, pA1);
    for (int t = 0; t < TT; t += 2) {
        STEP(t, pA0, pA1, pB0, pB1);
        if (t + 1 < TT) STEP(t + 1, pB0, pB1, pA0, pA1);
    }
}

extern "C" void kernel_launch(void* const* d_in, const int* in_sizes, int n_in,
                              void* d_out, int out_size, void* d_ws, size_t ws_size,
                              hipStream_t stream) {
    const float* enc_in = (const float*)d_in[0];
    const float* W_ih[3] = {(const float*)d_in[1], (const float*)d_in[5], (const float*)d_in[9]};
    const float* W_hh[3] = {(const float*)d_in[2], (const float*)d_in[6], (const float*)d_in[10]};
    const float* b_ih[3] = {(const float*)d_in[3], (const float*)d_in[7], (const float*)d_in[11]};
    const float* b_hh[3] = {(const float*)d_in[4], (const float*)d_in[8], (const float*)d_in[12]};
    float* out = (float*)d_out;

    char* ws = (char*)d_ws;
    size_t off = 0;
    auto alloc = [&](size_t bytes) {
        char* p = ws + off;
        off += (bytes + 255) & ~(size_t)255;
        return p;
    };
    f16* Wih_c[3];
    f16* Whh_c[3];
    Wih_c[0] = (f16*)alloc(4ull * NPAD * DIN * sizeof(f16));
    Whh_c[0] = (f16*)alloc(4ull * NPAD * NPAD * sizeof(f16));
    Wih_c[1] = (f16*)alloc(4ull * NPAD * NPAD * sizeof(f16));
    Whh_c[1] = (f16*)alloc(4ull * NPAD * NPAD * sizeof(f16));
    Wih_c[2] = (f16*)alloc(4ull * NPAD * NPAD * sizeof(f16));
    Whh_c[2] = (f16*)alloc(4ull * NPAD * NPAD * sizeof(f16));
    float* bias_c[3];
    for (int l = 0; l < 3; l++) bias_c[l] = (float*)alloc(4ull * NPAD * sizeof(float));
    f16* xbf = (f16*)alloc((size_t)TT * NB * DIN * sizeof(f16));
    f16* hall[3];
    for (int l = 0; l < 3; l++) hall[l] = (f16*)alloc((size_t)TT * NB * NPAD * sizeof(f16));
    f16* pre2 = (f16*)alloc((size_t)M_ALL * 4096 * sizeof(f16));
    unsigned int* flags = (unsigned int*)alloc(3ull * 8 * TT * sizeof(unsigned int));

    hipMemsetAsync(flags, 0, 3ull * 8 * TT * sizeof(unsigned int), stream);

    {
        int t8_l0 = 4 * NPAD * DIN / 8;
        conv_weight_v<<<(t8_l0 + 255) / 256, 256, 0, stream>>>(W_ih[0], Wih_c[0], DIN, DIN, t8_l0);
        int t8 = 4 * NPAD * NPAD / 8;
        conv_weight_v<<<(t8 + 255) / 256, 256, 0, stream>>>(W_hh[0], Whh_c[0], HID_, NPAD, t8);
        conv_weight_v<<<(t8 + 255) / 256, 256, 0, stream>>>(W_ih[1], Wih_c[1], HID_, NPAD, t8);
        conv_weight_v<<<(t8 + 255) / 256, 256, 0, stream>>>(W_hh[1], Whh_c[1], HID_, NPAD, t8);
        conv_weight_v<<<(t8 + 255) / 256, 256, 0, stream>>>(W_ih[2], Wih_c[2], HID_, NPAD, t8);
        conv_weight_v<<<(t8 + 255) / 256, 256, 0, stream>>>(W_hh[2], Whh_c[2], HID_, NPAD, t8);
    }
    {
        int t8x = TT * NB * (DIN / 8);
        conv_x_v<<<(t8x + 255) / 256, 256, 0, stream>>>(enc_in, xbf, t8x);
    }
    for (int l = 0; l < 3; l++)
        conv_bias<<<(4 * NPAD + 255) / 256, 256, 0, stream>>>(b_ih[l], b_hh[l], bias_c[l]);

    for (int l = 0; l < 3; l++) {
        if (l == 0)
            gemm8<<<784, 512, 0, stream>>>(xbf, DIN, DIN / 32, Wih_c[0], DIN,
                                           bias_c[0], pre2);
        else
            gemm8<<<784, 512, 0, stream>>>(hall[l - 1], NPAD, NPAD / 32, Wih_c[l], NPAD,
                                           bias_c[l], pre2);
        rec_persist<<<256, 512, 0, stream>>>(
            Whh_c[l], pre2, hall[l], out + (size_t)l * NB * TT * HID_,
            flags + (size_t)l * 8 * TT);
    }
}

// Round 18
// 1029.898 us; speedup vs baseline: 1.4279x; 1.0235x over previous
//
#include <hip/hip_runtime.h>

#define HID_ 1000
#define NB 256
#define TT 49
#define DIN 192
#define NPAD 1024
#define M_ALL (TT * 256)  // 12544

typedef _Float16 f16;
typedef _Float16 f16x4 __attribute__((ext_vector_type(4)));
typedef _Float16 f16x8 __attribute__((ext_vector_type(8)));
typedef float f32x4 __attribute__((ext_vector_type(4)));
typedef float f32x16 __attribute__((ext_vector_type(16)));
typedef const __attribute__((address_space(1))) unsigned int* gas_u32;
typedef __attribute__((address_space(3))) unsigned int* las_u32;

__device__ __forceinline__ float sigmf_(float x) {
    return 1.0f / (1.0f + __expf(-x));
}
__device__ __forceinline__ float tanhf_(float x) {
    float ax = fabsf(x);
    float e = __expf(-2.0f * ax);
    float t = (1.0f - e) / (1.0f + e);
    return copysignf(t, x);
}

// ---- fused prep: 6 weight converts + x convert + 3 biases + flag zero ----
__device__ __forceinline__ void convw_item(const float* __restrict__ src,
                                           f16* __restrict__ dst, int K, int KPADv,
                                           int idx) {
    const int kpw = KPADv >> 3;
    const int kp = (idx % kpw) << 3;
    const int rest = idx / kpw;          // g*1024 + np
    const int np = rest & 1023;
    f16x8 v = {};
    if (np < HID_ && kp < K) {
        const int g = rest >> 10;
        const float* sp = src + (size_t)(g * HID_ + np) * K + kp;
        float4 a = *(const float4*)sp;
        float4 b = *(const float4*)(sp + 4);
        v[0] = (f16)a.x; v[1] = (f16)a.y; v[2] = (f16)a.z; v[3] = (f16)a.w;
        v[4] = (f16)b.x; v[5] = (f16)b.y; v[6] = (f16)b.z; v[7] = (f16)b.w;
    }
    *(f16x8*)(dst + (size_t)rest * KPADv + kp) = v;
}

#define W0T8 (4 * NPAD * DIN / 8)    // 98304
#define WT8 (4 * NPAD * NPAD / 8)    // 524288
#define XT8 (TT * NB * (DIN / 8))    // 301056
#define BIAS_N (3 * 4 * NPAD)        // 12288
#define FLAG_N (3 * 8 * TT)          // 1176
#define PREP_TOTAL (W0T8 + 5 * WT8 + XT8 + BIAS_N + FLAG_N)

__global__ __launch_bounds__(256) void prep_all(
    const float* __restrict__ enc_in,
    const float* __restrict__ Wih0s, const float* __restrict__ Whh0s,
    const float* __restrict__ Wih1s, const float* __restrict__ Whh1s,
    const float* __restrict__ Wih2s, const float* __restrict__ Whh2s,
    const float* __restrict__ bih0, const float* __restrict__ bhh0,
    const float* __restrict__ bih1, const float* __restrict__ bhh1,
    const float* __restrict__ bih2, const float* __restrict__ bhh2,
    f16* __restrict__ Wih0d, f16* __restrict__ Whh0d,
    f16* __restrict__ Wih1d, f16* __restrict__ Whh1d,
    f16* __restrict__ Wih2d, f16* __restrict__ Whh2d,
    f16* __restrict__ xbf, float* __restrict__ biasd,
    unsigned int* __restrict__ flags) {
    int i = blockIdx.x * 256 + threadIdx.x;
    if (i >= PREP_TOTAL) return;
    if (i < W0T8) { convw_item(Wih0s, Wih0d, DIN, DIN, i); return; }
    i -= W0T8;
    if (i < WT8) { convw_item(Whh0s, Whh0d, HID_, NPAD, i); return; }
    i -= WT8;
    if (i < WT8) { convw_item(Wih1s, Wih1d, HID_, NPAD, i); return; }
    i -= WT8;
    if (i < WT8) { convw_item(Whh1s, Whh1d, HID_, NPAD, i); return; }
    i -= WT8;
    if (i < WT8) { convw_item(Wih2s, Wih2d, HID_, NPAD, i); return; }
    i -= WT8;
    if (i < WT8) { convw_item(Whh2s, Whh2d, HID_, NPAD, i); return; }
    i -= WT8;
    if (i < XT8) {
        const int kp = (i % (DIN / 8)) << 3;
        const int rest = i / (DIN / 8);  // t*NB + b
        const int b = rest & 255;
        const int t = rest >> 8;
        const float* sp = enc_in + ((size_t)b * TT + t) * DIN + kp;
        float4 a = *(const float4*)sp;
        float4 c = *(const float4*)(sp + 4);
        f16x8 v;
        v[0] = (f16)a.x; v[1] = (f16)a.y; v[2] = (f16)a.z; v[3] = (f16)a.w;
        v[4] = (f16)c.x; v[5] = (f16)c.y; v[6] = (f16)c.z; v[7] = (f16)c.w;
        *(f16x8*)(xbf + (size_t)rest * DIN + kp) = v;
        return;
    }
    i -= XT8;
    if (i < BIAS_N) {
        const int l = i / (4 * NPAD);
        const int li = i - l * 4 * NPAD;
        const int np = li & (NPAD - 1);
        const int g = li >> 10;
        float v = 0.0f;
        if (np < HID_) {
            const float* bi = (l == 0) ? bih0 : (l == 1) ? bih1 : bih2;
            const float* bh = (l == 0) ? bhh0 : (l == 1) ? bhh1 : bhh2;
            v = bi[g * HID_ + np] + bh[g * HID_ + np];
        }
        biasd[i] = v;
        return;
    }
    i -= BIAS_N;
    flags[i] = 0u;
}

// Pipelined GEMM: pre2 = A @ W^T + bias. 256x256 tile, BK=32, 4-buf LDS
// rotation, counted vmcnt (never 0 in steady state), raw barriers, setprio.
// r18: STAGE issued BEFORE the phase's ds_reads (T14 ordering) so the HBM
// latency overlaps ds_read+MFMA. Output scatter in rec's 32x32-frag order.
__global__ __launch_bounds__(512) void gemm8(
    const f16* __restrict__ A, int lda, int nkt,
    const f16* __restrict__ W, int ldw,
    const float* __restrict__ bias,
    f16* __restrict__ pre2) {
    __shared__ f16 lds[4][2][8192];  // [buf][A=0/B=1][256 rows x 32 k]
    const int id = blockIdx.x;
    const int sw = (id & 7) * (gridDim.x >> 3) + (id >> 3);  // 784 % 8 == 0
    const int mt = sw >> 4;   // 0..48
    const int nt = sw & 15;   // 0..15
    const int m0 = mt << 8, n0 = nt << 8;
    const int tid = threadIdx.x;
    const int w = tid >> 6, lane = tid & 63;
    const int r = lane & 15, u = lane >> 4;
    const int wr = w >> 2, wc = w & 3;

    const int srow = (w << 5) + (lane >> 2);
    const int pslot = lane & 3;

    f32x4 acc[8][4];
#pragma unroll
    for (int mf = 0; mf < 8; mf++)
#pragma unroll
        for (int nf = 0; nf < 4; nf++) acc[mf][nf] = (f32x4){0.f, 0.f, 0.f, 0.f};

    auto STAGE = [&](int kt, int o) {
        const int b = kt & 3;
        const int row = srow + (o << 4);
        const int ls = pslot ^ (row & 3);
        const f16* ga = A + (size_t)(m0 + row) * lda + kt * 32 + ls * 8;
        const f16* gb = W + (size_t)(n0 + row) * ldw + kt * 32 + ls * 8;
        f16* da = &lds[b][0][0] + (w << 10) + (o << 9);
        f16* db = &lds[b][1][0] + (w << 10) + (o << 9);
        __builtin_amdgcn_global_load_lds((gas_u32)ga, (las_u32)da, 16, 0, 0);
        __builtin_amdgcn_global_load_lds((gas_u32)gb, (las_u32)db, 16, 0, 0);
    };
    auto RDA = [&](int b, int fr) -> f16x8 {
        const int row = (wr << 7) + fr * 16 + r;
        return *(const f16x8*)(&lds[b][0][0] + row * 32 + ((u ^ (row & 3)) << 3));
    };
    auto RDB = [&](int b, int nf) -> f16x8 {
        const int row = (wc << 6) + nf * 16 + r;
        return *(const f16x8*)(&lds[b][1][0] + row * 32 + ((u ^ (row & 3)) << 3));
    };

    STAGE(0, 0); STAGE(0, 1); STAGE(1, 0); STAGE(1, 1);
    asm volatile("s_waitcnt vmcnt(4)" ::: "memory");
    __builtin_amdgcn_s_barrier();
    __builtin_amdgcn_sched_barrier(0);

    for (int kt = 0; kt < nkt; kt++) {
        const int b = kt & 3;
        const bool st = (kt + 2) < nkt;
        f16x8 bv[4], av[4];
        // ---- phase 0: M-half 0 (stage issued first: loads fly under reads+MFMA)
        if (st) STAGE(kt + 2, 0);
#pragma unroll
        for (int nf = 0; nf < 4; nf++) bv[nf] = RDB(b, nf);
#pragma unroll
        for (int mf = 0; mf < 4; mf++) av[mf] = RDA(b, mf);
        __builtin_amdgcn_s_barrier();
        __builtin_amdgcn_s_setprio(1);
#pragma unroll
        for (int mf = 0; mf < 4; mf++)
#pragma unroll
            for (int nf = 0; nf < 4; nf++)
                acc[mf][nf] = __builtin_amdgcn_mfma_f32_16x16x32_f16(
                    av[mf], bv[nf], acc[mf][nf], 0, 0, 0);
        __builtin_amdgcn_s_setprio(0);
        __builtin_amdgcn_s_barrier();
        // ---- phase 1: M-half 1 (B frags reused in regs)
        if (st) STAGE(kt + 2, 1);
#pragma unroll
        for (int mf = 0; mf < 4; mf++) av[mf] = RDA(b, 4 + mf);
        __builtin_amdgcn_s_barrier();
        __builtin_amdgcn_s_setprio(1);
#pragma unroll
        for (int mf = 0; mf < 4; mf++)
#pragma unroll
            for (int nf = 0; nf < 4; nf++)
                acc[4 + mf][nf] = __builtin_amdgcn_mfma_f32_16x16x32_f16(
                    av[mf], bv[nf], acc[4 + mf][nf], 0, 0, 0);
        __builtin_amdgcn_s_setprio(0);
        if (st) asm volatile("s_waitcnt vmcnt(4)" ::: "memory");
        else    asm volatile("s_waitcnt vmcnt(0)" ::: "memory");
        __builtin_amdgcn_s_barrier();
        __builtin_amdgcn_sched_barrier(0);
    }

#pragma unroll
    for (int nf = 0; nf < 4; nf++) {
        const int gcol = n0 + (wc << 6) + nf * 16 + r;
        const float bj = bias[gcol];
        const int g = gcol >> 10;
        const int jt2 = (gcol & 1023) >> 5;
        const int col32 = gcol & 31;
        const int lane2 = col32 + ((u & 1) << 5);
#pragma unroll
        for (int mf = 0; mf < 8; mf++) {
            const int grow = m0 + (wr << 7) + mf * 16 + (u << 2);  // q=0 row
            const int bt2 = (grow >> 5) & 7;
            const int regbase = ((mf & 1) << 3) + ((u >> 1) << 2);
            f16x4 hv;
#pragma unroll
            for (int q = 0; q < 4; q++) hv[q] = (f16)(acc[mf][nf][q] + bj);
            *(f16x4*)(pre2 + ((((size_t)mt * 8 + bt2) * 32 + jt2) * 4 + g) * 1024 +
                      lane2 * 16 + regbase) = hv;
        }
    }
}

// Persistent per-layer recurrent kernel — r14/r15 version verbatim (best: 238us).
__global__ __launch_bounds__(512, 2) void rec_persist(
    const f16* __restrict__ Whh, const f16* __restrict__ pre2,
    f16* __restrict__ hall, float* __restrict__ outl,
    unsigned int* __restrict__ flags) {
    __shared__ __align__(16) char smem[64 * 1024];  // h tile [32 rows][2048B] XOR5-swizzled
    __shared__ float pl[2 * 4 * 32 * 34];           // [kh][gate][row][34] partials
    const int bid = blockIdx.x;
    const int bt = bid & 7;
    const int jt = bid >> 3;
    const int b0 = bt << 5;
    const int jc0 = jt << 5;
    const int tid = threadIdx.x;
    const int w = tid >> 6;
    const int g = w >> 1;
    const int kh = w & 1;
    const int lane = tid & 63;
    const int row = lane & 31;
    const int kg = lane >> 5;

    f16x8 wreg[32];
    {
        const f16* wp = Whh + ((size_t)(g * NPAD + jc0 + row)) * NPAD + (kh << 9) + (kg << 3);
#pragma unroll
        for (int ks = 0; ks < 32; ks++) wreg[ks] = *(const f16x8*)(wp + ks * 16);
    }

    const int eb = tid >> 4;
    const int ej = (tid & 15) << 1;
    float cv[2] = {0.f, 0.f};
    unsigned int* myflags = flags + bt * TT;
    const size_t preblk = ((((size_t)bt) * 32 + jt) * 4 + g) * 1024 + lane * 16;

    auto LOADP = [&](int tindex, f16x8& pa, f16x8& pb) {
        if (kh == 0) {
            const f16* pp = pre2 + (size_t)tindex * 8 * 32 * 4 * 1024 + preblk;
            pa = *(const f16x8*)pp;
            pb = *(const f16x8*)(pp + 8);
        }
    };

    auto STEP = [&](int t, f16x8& pc0, f16x8& pc1, f16x8& pn0, f16x8& pn1) {
        LOADP(t + 1 < TT ? t + 1 : t, pn0, pn1);

        if (t > 0) {
            while (__hip_atomic_load(myflags + (t - 1), __ATOMIC_RELAXED,
                                     __HIP_MEMORY_SCOPE_AGENT) < 32u) {}
            asm volatile("" ::: "memory");
            const f16* hread = hall + (size_t)(t - 1) * NB * NPAD;
#pragma unroll
            for (int i = 0; i < 8; i++) {
                int c = tid + (i << 9);
                int srow = c >> 7;
                int cb = (c & 127) << 4;
                f16x8 v = *(const f16x8*)(hread + (size_t)(b0 + srow) * NPAD + (cb >> 1));
                *(f16x8*)(smem + srow * 2048 + (cb ^ (srow << 4))) = v;
            }
        }
        __syncthreads();  // B1: h tile staged

        f32x16 acc;
#pragma unroll
        for (int reg = 0; reg < 16; reg++)
            acc[reg] = (kh == 0) ? (float)(reg < 8 ? pc0[reg] : pc1[reg - 8]) : 0.f;

        if (t > 0) {
#pragma unroll
            for (int ks = 0; ks < 32; ks++) {
                const int bc = (kh << 10) + ks * 32 + (kg << 4);
                f16x8 a = *(const f16x8*)(smem + row * 2048 + (bc ^ (row << 4)));
                acc = __builtin_amdgcn_mfma_f32_32x32x16_f16(a, wreg[ks], acc, 0, 0, 0);
            }
        }

#pragma unroll
        for (int reg = 0; reg < 16; reg++) {
            const int prow = (reg & 3) + ((reg >> 2) << 3) + (kg << 2);
            pl[((kh * 4 + g) * 32 + prow) * 34 + row] = acc[reg];
        }
        __syncthreads();  // B2: partials ready

        float hvv[2];
        {
            float gv[4][2];
#pragma unroll
            for (int gate = 0; gate < 4; gate++) {
                float2 p0 = *(const float2*)&pl[((0 * 4 + gate) * 32 + eb) * 34 + ej];
                float2 p1 = *(const float2*)&pl[((1 * 4 + gate) * 32 + eb) * 34 + ej];
                gv[gate][0] = p0.x + p1.x;
                gv[gate][1] = p0.y + p1.y;
            }
#pragma unroll
            for (int q = 0; q < 2; q++) {
                float cn = sigmf_(gv[1][q]) * cv[q] + sigmf_(gv[0][q]) * tanhf_(gv[2][q]);
                hvv[q] = sigmf_(gv[3][q]) * tanhf_(cn);
                cv[q] = cn;
            }
        }
        {
            union { f16 h2[2]; unsigned uu; } cvt;
            cvt.h2[0] = (f16)hvv[0];
            cvt.h2[1] = (f16)hvv[1];
            __hip_atomic_store(
                (unsigned*)(hall + ((size_t)t * NB + b0 + eb) * NPAD + jc0 + ej), cvt.uu,
                __ATOMIC_RELAXED, __HIP_MEMORY_SCOPE_AGENT);
        }
        __syncthreads();  // B3: vmcnt drained -> h stores visible; pl reads done
        if (tid == 0)
            __hip_atomic_fetch_add(myflags + t, 1u, __ATOMIC_RELAXED, __HIP_MEMORY_SCOPE_AGENT);
        const int col = jc0 + ej;
        if (col < HID_) {
            *(float2*)(outl + ((size_t)(b0 + eb) * TT + t) * HID_ + col) =
                make_float2(hvv[0], hvv[1]);
        }
    };

    f16x8 pA0 = {}, pA1 = {}, pB0 = {}, pB1 = {};
    LOADP(0, pA0, pA1);
    for (int t = 0; t < TT; t += 2) {
        STEP(t, pA0, pA1, pB0, pB1);
        if (t + 1 < TT) STEP(t + 1, pB0, pB1, pA0, pA1);
    }
}

extern "C" void kernel_launch(void* const* d_in, const int* in_sizes, int n_in,
                              void* d_out, int out_size, void* d_ws, size_t ws_size,
                              hipStream_t stream) {
    const float* enc_in = (const float*)d_in[0];
    const float* W_ih[3] = {(const float*)d_in[1], (const float*)d_in[5], (const float*)d_in[9]};
    const float* W_hh[3] = {(const float*)d_in[2], (const float*)d_in[6], (const float*)d_in[10]};
    const float* b_ih[3] = {(const float*)d_in[3], (const float*)d_in[7], (const float*)d_in[11]};
    const float* b_hh[3] = {(const float*)d_in[4], (const float*)d_in[8], (const float*)d_in[12]};
    float* out = (float*)d_out;

    char* ws = (char*)d_ws;
    size_t off = 0;
    auto alloc = [&](size_t bytes) {
        char* p = ws + off;
        off += (bytes + 255) & ~(size_t)255;
        return p;
    };
    f16* Wih_c[3];
    f16* Whh_c[3];
    Wih_c[0] = (f16*)alloc(4ull * NPAD * DIN * sizeof(f16));
    Whh_c[0] = (f16*)alloc(4ull * NPAD * NPAD * sizeof(f16));
    Wih_c[1] = (f16*)alloc(4ull * NPAD * NPAD * sizeof(f16));
    Whh_c[1] = (f16*)alloc(4ull * NPAD * NPAD * sizeof(f16));
    Wih_c[2] = (f16*)alloc(4ull * NPAD * NPAD * sizeof(f16));
    Whh_c[2] = (f16*)alloc(4ull * NPAD * NPAD * sizeof(f16));
    float* bias_c = (float*)alloc(3ull * 4 * NPAD * sizeof(float));  // [l][4][NPAD]
    f16* xbf = (f16*)alloc((size_t)TT * NB * DIN * sizeof(f16));
    f16* hall[3];
    for (int l = 0; l < 3; l++) hall[l] = (f16*)alloc((size_t)TT * NB * NPAD * sizeof(f16));
    f16* pre2 = (f16*)alloc((size_t)M_ALL * 4096 * sizeof(f16));
    unsigned int* flags = (unsigned int*)alloc(3ull * 8 * TT * sizeof(unsigned int));

    prep_all<<<(PREP_TOTAL + 255) / 256, 256, 0, stream>>>(
        enc_in, W_ih[0], W_hh[0], W_ih[1], W_hh[1], W_ih[2], W_hh[2],
        b_ih[0], b_hh[0], b_ih[1], b_hh[1], b_ih[2], b_hh[2],
        Wih_c[0], Whh_c[0], Wih_c[1], Whh_c[1], Wih_c[2], Whh_c[2],
        xbf, bias_c, flags);

    for (int l = 0; l < 3; l++) {
        if (l == 0)
            gemm8<<<784, 512, 0, stream>>>(xbf, DIN, DIN / 32, Wih_c[0], DIN,
                                           bias_c, pre2);
        else
            gemm8<<<784, 512, 0, stream>>>(hall[l - 1], NPAD, NPAD / 32, Wih_c[l], NPAD,
                                           bias_c + (size_t)l * 4 * NPAD, pre2);
        rec_persist<<<256, 512, 0, stream>>>(
            Whh_c[l], pre2, hall[l], out + (size_t)l * NB * TT * HID_,
            flags + (size_t)l * 8 * TT);
    }
}